// Round 1
// 223.271 us; speedup vs baseline: 1.0546x; 1.0546x over previous
//
#include <hip/hip_runtime.h>
#include <hip/hip_bf16.h>
#include <stdint.h>

typedef __attribute__((ext_vector_type(8))) short bf16x8;
typedef __attribute__((ext_vector_type(4))) float f32x4;
typedef __attribute__((ext_vector_type(4))) unsigned short u16x4;

#define B_ 4
#define T_ 2048
#define C_ 1024
#define H_ 16
#define D_ 64

// round-to-nearest-even fp32 -> bf16
__device__ __forceinline__ unsigned short f2bf(float f) {
  union { float f; uint32_t u; } v; v.f = f;
  uint32_t u = v.u;
  uint32_t r = (u + 0x7FFFu + ((u >> 16) & 1u)) >> 16;
  return (unsigned short)r;
}

__global__ void __launch_bounds__(256) cast_f32_bf16(const float* __restrict__ src,
                                                     unsigned short* __restrict__ dst,
                                                     int n4) {
  int i = blockIdx.x * 256 + threadIdx.x;
  if (i >= n4) return;
  float4 f = ((const float4*)src)[i];
  u16x4 o;
  o[0] = f2bf(f.x); o[1] = f2bf(f.y); o[2] = f2bf(f.z); o[3] = f2bf(f.w);
  ((u16x4*)dst)[i] = o;
}

// C = A[M,K=1024] * B[N,K=1024]^T, bf16 in, fp32 acc.
// m97-structure: 128x128 tile, BK=32, 256 threads (2x2 waves, each 64x64 = 4x4 mfma tiles).
// Staging via __builtin_amdgcn_global_load_lds width=16 (no VGPR round-trip).
// LDS layout LINEAR [128][32] shorts (64 B rows) -- required: gload_lds writes
// wave-uniform base + lane*16B. 16 chunks of 1 KiB (16 rows each); wave w issues
// chunks 4w..4w+3 (waves 0-1: A, waves 2-3: B). Lane l covers row l>>2, col (l&3)*8
// within its chunk -> LDS byte offset 16*l, exactly the HW pattern.
// ds_read_b128 fragment reads are ~8-way bank-conflicted on this layout; known-null
// at the 2-barrier structure (regime gate: T2 only pays at 8-phase).
// MODE 0: scatter-epilogue to q/k/v [B,H,T,D] bf16.  MODE 1: plain fp32 store.
template <int MODE>
__global__ void __launch_bounds__(256) gemm_bt(const unsigned short* __restrict__ A,
                                               const unsigned short* __restrict__ Bm,
                                               unsigned short* __restrict__ qb,
                                               unsigned short* __restrict__ kb,
                                               unsigned short* __restrict__ vb,
                                               float* __restrict__ fo) {
  __shared__ short As[128 * 32];
  __shared__ short Bs[128 * 32];
  const int tid = threadIdx.x;
  const int bm = blockIdx.y * 128;
  const int bn = blockIdx.x * 128;
  const int wave = tid >> 6;
  const int l = tid & 63;
  const int wm = wave >> 1, wn = wave & 1;
  const int lm = l & 15, lq = l >> 4;
  const int lr = l >> 2;           // row within 16-row chunk
  const int lc = (l & 3) << 3;     // k-col {0,8,16,24}

  f32x4 acc[4][4];
#pragma unroll
  for (int i = 0; i < 4; i++)
#pragma unroll
    for (int j = 0; j < 4; j++) acc[i][j] = (f32x4){0.f, 0.f, 0.f, 0.f};

  // per-wave staging chunk setup (wave-uniform LDS bases, per-lane global src)
  const unsigned short* gsrc[4];
  short* ldst[4];
#pragma unroll
  for (int i = 0; i < 4; i++) {
    int c = wave * 4 + i;            // 0..15, wave-uniform
    if (c < 8) {
      gsrc[i] = A + (size_t)(bm + 16 * c + lr) * 1024 + lc;
      ldst[i] = &As[(16 * c) * 32];
    } else {
      gsrc[i] = Bm + (size_t)(bn + 16 * (c - 8) + lr) * 1024 + lc;
      ldst[i] = &Bs[(16 * (c - 8)) * 32];
    }
  }

  for (int k0 = 0; k0 < 1024; k0 += 32) {
    __syncthreads();  // previous tile fully consumed before overwrite
#pragma unroll
    for (int i = 0; i < 4; i++) {
      __builtin_amdgcn_global_load_lds(
          (__attribute__((address_space(1))) void*)(uintptr_t)(const void*)(gsrc[i] + k0),
          (__attribute__((address_space(3))) void*)(ldst[i]),
          16, 0, 0);
    }
    __syncthreads();  // compiler drains vmcnt(0) before barrier -> tile ready
    bf16x8 af[4], bfr[4];
#pragma unroll
    for (int i = 0; i < 4; i++)
      af[i] = *(const bf16x8*)&As[(wm * 64 + 16 * i + lm) * 32 + 8 * lq];
#pragma unroll
    for (int j = 0; j < 4; j++)
      bfr[j] = *(const bf16x8*)&Bs[(wn * 64 + 16 * j + lm) * 32 + 8 * lq];
#pragma unroll
    for (int i = 0; i < 4; i++)
#pragma unroll
      for (int j = 0; j < 4; j++)
        acc[i][j] = __builtin_amdgcn_mfma_f32_16x16x32_bf16(af[i], bfr[j], acc[i][j], 0, 0, 0);
  }

  // C/D layout: col = lane&15, row = (lane>>4)*4 + reg  [measured m89/m91]
#pragma unroll
  for (int i = 0; i < 4; i++) {
#pragma unroll
    for (int j = 0; j < 4; j++) {
#pragma unroll
      for (int r = 0; r < 4; r++) {
        int m = bm + wm * 64 + 16 * i + 4 * lq + r;
        int n = bn + wn * 64 + 16 * j + lm;
        float val = acc[i][j][r];
        if (MODE == 0) {
          int which = n >> 10, rem = n & 1023;
          int h = rem >> 6, d = rem & 63;
          int b = m >> 11, t = m & 2047;
          unsigned short* dst = (which == 0) ? qb : ((which == 1) ? kb : vb);
          dst[(((size_t)(b * 16 + h)) * 2048 + t) * 64 + d] = f2bf(val);
        } else {
          fo[(size_t)m * 1024 + n] = val;
        }
      }
    }
  }
}

// Sliding-window causal flash attention.
// One wave per (b,h, 16-query tile); 32-key chunks; online softmax in base 2.
// q/k/v in [B,H,T,D] bf16; output [B,T,H*D] bf16.
__global__ void __launch_bounds__(256) attn_swa(const unsigned short* __restrict__ Qb,
                                               const unsigned short* __restrict__ Kb,
                                               const unsigned short* __restrict__ Vb,
                                               unsigned short* __restrict__ Ob) {
  __shared__ short P[4][16 * 40];  // per-wave P tile, row stride 40 (16B-aligned rows)
  const int wv = threadIdx.x >> 6;
  const int l = threadIdx.x & 63;
  const int wid = blockIdx.x * 4 + wv;
  const int bh = wid >> 7;           // 128 q-tiles per (b,h)
  const int t0 = (wid & 127) << 4;
  const int lm = l & 15, lq = l >> 4;
  const size_t base = (size_t)bh * (T_ * D_);

  // Q A-fragments: A[m=lane&15][k=quad*8+j], two k-halves (d 0..31, 32..63)
  bf16x8 aq0 = *(const bf16x8*)(Qb + base + (size_t)(t0 + lm) * 64 + 8 * lq);
  bf16x8 aq1 = *(const bf16x8*)(Qb + base + (size_t)(t0 + lm) * 64 + 32 + 8 * lq);

  float mst[4], lst[4];
  f32x4 Oa[4];
#pragma unroll
  for (int r = 0; r < 4; r++) { mst[r] = -1e30f; lst[r] = 0.f; }
#pragma unroll
  for (int jt = 0; jt < 4; jt++) Oa[jt] = (f32x4){0.f, 0.f, 0.f, 0.f};

  const float cs = 0.125f * 1.44269504f;  // scale * log2(e)
  int jstart = t0 - 128; if (jstart < 0) jstart = 0;

  for (int j0 = jstart; j0 < t0 + 16; j0 += 32) {
    f32x4 S[2];
#pragma unroll
    for (int hh = 0; hh < 2; hh++) {
      int kr = j0 + 16 * hh + lm; if (kr > T_ - 1) kr = T_ - 1;  // OOB rows are causal-masked
      bf16x8 bk0 = *(const bf16x8*)(Kb + base + (size_t)kr * 64 + 8 * lq);
      bf16x8 bk1 = *(const bf16x8*)(Kb + base + (size_t)kr * 64 + 32 + 8 * lq);
      f32x4 s = (f32x4){0.f, 0.f, 0.f, 0.f};
      s = __builtin_amdgcn_mfma_f32_16x16x32_bf16(aq0, bk0, s, 0, 0, 0);
      s = __builtin_amdgcn_mfma_f32_16x16x32_bf16(aq1, bk1, s, 0, 0, 0);
      S[hh] = s;
    }
    float p0s[4], p1s[4], al[4];
#pragma unroll
    for (int r = 0; r < 4; r++) {
      int t = t0 + 4 * lq + r;
      int ja = j0 + lm, jb = j0 + 16 + lm;
      float s0 = ((ja <= t) && (ja + 128 >= t)) ? S[0][r] * cs : -1e30f;
      float s1 = ((jb <= t) && (jb + 128 >= t)) ? S[1][r] * cs : -1e30f;
      float m2 = fmaxf(s0, s1);
#pragma unroll
      for (int off = 1; off < 16; off <<= 1) m2 = fmaxf(m2, __shfl_xor(m2, off));
      float mn = fmaxf(mst[r], m2);
      float a = __builtin_amdgcn_exp2f(mst[r] - mn);
      float p0 = __builtin_amdgcn_exp2f(s0 - mn);
      float p1 = __builtin_amdgcn_exp2f(s1 - mn);
      float ps = p0 + p1;
#pragma unroll
      for (int off = 1; off < 16; off <<= 1) ps += __shfl_xor(ps, off);
      lst[r] = lst[r] * a + ps;
      mst[r] = mn;
      al[r] = a; p0s[r] = p0; p1s[r] = p1;
    }
#pragma unroll
    for (int jt = 0; jt < 4; jt++)
#pragma unroll
      for (int r = 0; r < 4; r++) Oa[jt][r] *= al[r];
    // P: C-layout -> LDS -> A-layout (per m120); same-wave LDS, no barrier needed
#pragma unroll
    for (int r = 0; r < 4; r++) {
      P[wv][(4 * lq + r) * 40 + lm] = (short)f2bf(p0s[r]);
      P[wv][(4 * lq + r) * 40 + 16 + lm] = (short)f2bf(p1s[r]);
    }
    bf16x8 pa = *(const bf16x8*)&P[wv][lm * 40 + 8 * lq];
#pragma unroll
    for (int jt = 0; jt < 4; jt++) {
      bf16x8 vf;  // B-frag: V[k=quad*8+jj][n=16*jt+lm] (transposed gather, L1-served)
#pragma unroll
      for (int jj = 0; jj < 8; jj++) {
        int kk = j0 + 8 * lq + jj; if (kk > T_ - 1) kk = T_ - 1;
        vf[jj] = (short)Vb[base + (size_t)kk * 64 + 16 * jt + lm];
      }
      Oa[jt] = __builtin_amdgcn_mfma_f32_16x16x32_bf16(pa, vf, Oa[jt], 0, 0, 0);
    }
  }
  const int b = bh >> 4, h = bh & 15;
#pragma unroll
  for (int r = 0; r < 4; r++) {
    float inv = 1.0f / lst[r];
    int t = t0 + 4 * lq + r;
#pragma unroll
    for (int jt = 0; jt < 4; jt++) {
      int c = h * 64 + 16 * jt + lm;
      Ob[((size_t)(b * T_ + t)) * 1024 + c] = f2bf(Oa[jt][r] * inv);
    }
  }
}

extern "C" void kernel_launch(void* const* d_in, const int* in_sizes, int n_in,
                              void* d_out, int out_size, void* d_ws, size_t ws_size,
                              hipStream_t stream) {
  const float* x = (const float*)d_in[0];       // [4,2048,1024]
  const float* w_qkv = (const float*)d_in[1];   // [3072,1024]
  const float* w_out = (const float*)d_in[2];   // [1024,1024]
  float* out = (float*)d_out;                   // [4,2048,1024] fp32

  // workspace layout (bf16 = unsigned short), ~72 MB total
  unsigned short* xb = (unsigned short*)d_ws;                // 8192*1024 (reused as attn out)
  unsigned short* wqkvb = xb + (size_t)8192 * 1024;          // 3072*1024
  unsigned short* woutb = wqkvb + (size_t)3072 * 1024;       // 1024*1024
  unsigned short* qb = woutb + (size_t)1024 * 1024;          // 64*2048*64
  unsigned short* kb = qb + (size_t)64 * 2048 * 64;
  unsigned short* vb = kb + (size_t)64 * 2048 * 64;

  cast_f32_bf16<<<8192, 256, 0, stream>>>(x, xb, 8192 * 1024 / 4);
  cast_f32_bf16<<<3072, 256, 0, stream>>>(w_qkv, wqkvb, 3072 * 1024 / 4);
  cast_f32_bf16<<<1024, 256, 0, stream>>>(w_out, woutb, 1024 * 1024 / 4);

  // qkv = x @ w_qkv^T, scattered to q/k/v [B,H,T,D]
  gemm_bt<0><<<dim3(24, 64), 256, 0, stream>>>(xb, wqkvb, qb, kb, vb, nullptr);

  // sliding-window attention -> [B,T,C] bf16 (aliases xb; xb is dead after gemm_qkv)
  attn_swa<<<2048, 256, 0, stream>>>(qb, kb, vb, xb);

  // out = attn @ w_out^T (fp32 store)
  gemm_bt<1><<<dim3(8, 64), 256, 0, stream>>>(xb, woutb, nullptr, nullptr, nullptr, out);
}

// Round 3
// 219.373 us; speedup vs baseline: 1.0733x; 1.0178x over previous
//
#include <hip/hip_runtime.h>
#include <hip/hip_bf16.h>
#include <stdint.h>

typedef __attribute__((ext_vector_type(8))) short bf16x8;
typedef __attribute__((ext_vector_type(4))) float f32x4;
typedef __attribute__((ext_vector_type(4))) unsigned short u16x4;

#define B_ 4
#define T_ 2048
#define C_ 1024
#define H_ 16
#define D_ 64

// round-to-nearest-even fp32 -> bf16
__device__ __forceinline__ unsigned short f2bf(float f) {
  union { float f; uint32_t u; } v; v.f = f;
  uint32_t u = v.u;
  uint32_t r = (u + 0x7FFFu + ((u >> 16) & 1u)) >> 16;
  return (unsigned short)r;
}

__global__ void __launch_bounds__(256) cast_f32_bf16(const float* __restrict__ src,
                                                     unsigned short* __restrict__ dst,
                                                     int n4) {
  int i = blockIdx.x * 256 + threadIdx.x;
  if (i >= n4) return;
  float4 f = ((const float4*)src)[i];
  u16x4 o;
  o[0] = f2bf(f.x); o[1] = f2bf(f.y); o[2] = f2bf(f.z); o[3] = f2bf(f.w);
  ((u16x4*)dst)[i] = o;
}

// C = A[M,K=1024] * B[N,K=1024]^T, bf16 in, fp32 acc.
// 128x128 tile, BK=32, 256 threads (2x2 waves, each 64x64 = 4x4 mfma tiles).
// 2-PHASE double-buffered staging via global_load_lds width=16:
//   prologue STAGE(buf0); barrier;
//   loop: STAGE(buf^1, next) -> compute(buf cur) -> __syncthreads (drains vmcnt) -> flip.
// Next-tile HBM latency hides under current tile's ds_read+MFMA; one barrier per step.
// LDS: A buf0 @0, A buf1 @4096, B buf0 @8192, B buf1 @12288 (shorts, linear [128][32]
// per buffer as required by gload_lds wave-uniform-dest rule). Epilogue reuses LDS as a
// 128x132 bf16 tile for coalesced full-line output stores (kills write-allocate refetch).
// T1 XCD swizzle: bijective (nwg%8==0), column-strip chunks -> per-XCD B-slice L2-resident.
// MODE 0: q/k/v [B,H,T,D] bf16 scatter (via LDS transpose).  MODE 1: plain fp32 store.
template <int MODE>
__global__ void __launch_bounds__(256) gemm_bt(const unsigned short* __restrict__ A,
                                               const unsigned short* __restrict__ Bm,
                                               unsigned short* __restrict__ qb,
                                               unsigned short* __restrict__ kb,
                                               unsigned short* __restrict__ vb,
                                               float* __restrict__ fo) {
  __shared__ short lds[16896];  // loop: 16384 shorts (2x2 bufs); epilogue: 128*132=16896
  const int tid = threadIdx.x;

  // --- T1 XCD-aware swizzle (both launches use gridDim.y == 64) ---
  const int nwgx = gridDim.x;
  int flat = blockIdx.y * nwgx + blockIdx.x;
  int cpx = (nwgx << 6) >> 3;              // nwg/8 (nwg%8==0 for 24x64 and 8x64)
  int swz = (flat & 7) * cpx + (flat >> 3);
  const int bm = (swz & 63) * 128;         // m-fast within each XCD chunk
  const int bn = (swz >> 6) * 128;         // -> per-XCD column strip (B L2-resident)

  const int wave = tid >> 6;
  const int l = tid & 63;
  const int wm = wave >> 1, wn = wave & 1;
  const int lm = l & 15, lq = l >> 4;
  const int lr = l >> 2;           // row within 16-row staging chunk
  const int lc = (l & 3) << 3;     // k-col {0,8,16,24}

  f32x4 acc[4][4];
#pragma unroll
  for (int i = 0; i < 4; i++)
#pragma unroll
    for (int j = 0; j < 4; j++) acc[i][j] = (f32x4){0.f, 0.f, 0.f, 0.f};

  // per-wave staging chunks: wave 0-1 -> A, wave 2-3 -> B; LDS dest = uniform base + 16*lane
  const unsigned short* gsrc[4];
  int ldoff[4];
#pragma unroll
  for (int i = 0; i < 4; i++) {
    int c = wave * 4 + i;            // 0..15, wave-uniform
    if (c < 8) {
      gsrc[i] = A + (size_t)(bm + 16 * c + lr) * 1024 + lc;
      ldoff[i] = (16 * c) * 32;
    } else {
      gsrc[i] = Bm + (size_t)(bn + 16 * (c - 8) + lr) * 1024 + lc;
      ldoff[i] = 8192 + (16 * (c - 8)) * 32;
    }
  }

#define STAGE(curb, kk)                                                          \
  do {                                                                           \
    _Pragma("unroll")                                                            \
    for (int i = 0; i < 4; i++) {                                                \
      __builtin_amdgcn_global_load_lds(                                          \
          (__attribute__((address_space(1))) void*)(uintptr_t)(const void*)(gsrc[i] + (kk)), \
          (__attribute__((address_space(3))) void*)(lds + ldoff[i] + (curb) * 4096),         \
          16, 0, 0);                                                             \
    }                                                                            \
  } while (0)

  STAGE(0, 0);
  int cur = 0;
  __syncthreads();  // prologue tile landed (vmcnt(0) drain) + visible to all

  for (int k0 = 0; k0 < 1024; k0 += 32) {
    if (k0 + 32 < 1024) STAGE(cur ^ 1, k0 + 32);  // issue next tile EARLY
    bf16x8 af[4], bfr[4];
#pragma unroll
    for (int i = 0; i < 4; i++)
      af[i] = *(const bf16x8*)&lds[cur * 4096 + (wm * 64 + 16 * i + lm) * 32 + 8 * lq];
#pragma unroll
    for (int j = 0; j < 4; j++)
      bfr[j] = *(const bf16x8*)&lds[8192 + cur * 4096 + (wn * 64 + 16 * j + lm) * 32 + 8 * lq];
#pragma unroll
    for (int i = 0; i < 4; i++)
#pragma unroll
      for (int j = 0; j < 4; j++)
        acc[i][j] = __builtin_amdgcn_mfma_f32_16x16x32_bf16(af[i], bfr[j], acc[i][j], 0, 0, 0);
    __syncthreads();  // next tile's loads drained + everyone done reading cur
    cur ^= 1;
  }
#undef STAGE

  // C/D layout: col = lane&15, row = (lane>>4)*4 + reg  [measured m89/m91]
  if (MODE == 0) {
    // epilogue transpose: acc -> LDS bf16 [128][132] -> coalesced 16B/lane stores
#pragma unroll
    for (int i = 0; i < 4; i++)
#pragma unroll
      for (int j = 0; j < 4; j++)
#pragma unroll
        for (int r = 0; r < 4; r++)
          lds[(wm * 64 + 16 * i + 4 * lq + r) * 132 + wn * 64 + 16 * j + lm] =
              (short)f2bf(acc[i][j][r]);
    __syncthreads();
    // 2048 chunks of 8 shorts; thread handles chunks tid + 256k (rows coalesced)
#pragma unroll
    for (int k = 0; k < 8; k++) {
      int c = tid + 256 * k;
      int row = c >> 4;            // 0..127 (16 chunks per 128-short row)
      int col = (c & 15) << 3;     // 0..120
      bf16x8 v = *(const bf16x8*)&lds[row * 132 + col];
      int m = bm + row, n = bn + col;
      int which = n >> 10, rem = n & 1023;
      int h = rem >> 6, d = rem & 63;      // d 8-aligned, d+8 <= 64
      int b = m >> 11, t = m & 2047;
      unsigned short* dst = (which == 0) ? qb : ((which == 1) ? kb : vb);
      *(bf16x8*)&dst[(((size_t)(b * 16 + h)) * 2048 + t) * 64 + d] = v;
    }
  } else {
#pragma unroll
    for (int i = 0; i < 4; i++)
#pragma unroll
      for (int j = 0; j < 4; j++)
#pragma unroll
        for (int r = 0; r < 4; r++) {
          int m = bm + wm * 64 + 16 * i + 4 * lq + r;
          int n = bn + wn * 64 + 16 * j + lm;
          fo[(size_t)m * 1024 + n] = acc[i][j][r];
        }
  }
}

// Sliding-window causal flash attention.
// One wave per (b,h, 16-query tile); 32-key chunks; online softmax in base 2.
// q/k/v in [B,H,T,D] bf16; output [B,T,H*D] bf16.
__global__ void __launch_bounds__(256) attn_swa(const unsigned short* __restrict__ Qb,
                                               const unsigned short* __restrict__ Kb,
                                               const unsigned short* __restrict__ Vb,
                                               unsigned short* __restrict__ Ob) {
  __shared__ short P[4][16 * 40];  // per-wave P tile, row stride 40 (16B-aligned rows)
  const int wv = threadIdx.x >> 6;
  const int l = threadIdx.x & 63;
  const int wid = blockIdx.x * 4 + wv;
  const int bh = wid >> 7;           // 128 q-tiles per (b,h)
  const int t0 = (wid & 127) << 4;
  const int lm = l & 15, lq = l >> 4;
  const size_t base = (size_t)bh * (T_ * D_);

  // Q A-fragments: A[m=lane&15][k=quad*8+j], two k-halves (d 0..31, 32..63)
  bf16x8 aq0 = *(const bf16x8*)(Qb + base + (size_t)(t0 + lm) * 64 + 8 * lq);
  bf16x8 aq1 = *(const bf16x8*)(Qb + base + (size_t)(t0 + lm) * 64 + 32 + 8 * lq);

  float mst[4], lst[4];
  f32x4 Oa[4];
#pragma unroll
  for (int r = 0; r < 4; r++) { mst[r] = -1e30f; lst[r] = 0.f; }
#pragma unroll
  for (int jt = 0; jt < 4; jt++) Oa[jt] = (f32x4){0.f, 0.f, 0.f, 0.f};

  const float cs = 0.125f * 1.44269504f;  // scale * log2(e)
  int jstart = t0 - 128; if (jstart < 0) jstart = 0;

  for (int j0 = jstart; j0 < t0 + 16; j0 += 32) {
    f32x4 S[2];
#pragma unroll
    for (int hh = 0; hh < 2; hh++) {
      int kr = j0 + 16 * hh + lm; if (kr > T_ - 1) kr = T_ - 1;  // OOB rows are causal-masked
      bf16x8 bk0 = *(const bf16x8*)(Kb + base + (size_t)kr * 64 + 8 * lq);
      bf16x8 bk1 = *(const bf16x8*)(Kb + base + (size_t)kr * 64 + 32 + 8 * lq);
      f32x4 s = (f32x4){0.f, 0.f, 0.f, 0.f};
      s = __builtin_amdgcn_mfma_f32_16x16x32_bf16(aq0, bk0, s, 0, 0, 0);
      s = __builtin_amdgcn_mfma_f32_16x16x32_bf16(aq1, bk1, s, 0, 0, 0);
      S[hh] = s;
    }
    float p0s[4], p1s[4], al[4];
#pragma unroll
    for (int r = 0; r < 4; r++) {
      int t = t0 + 4 * lq + r;
      int ja = j0 + lm, jb = j0 + 16 + lm;
      float s0 = ((ja <= t) && (ja + 128 >= t)) ? S[0][r] * cs : -1e30f;
      float s1 = ((jb <= t) && (jb + 128 >= t)) ? S[1][r] * cs : -1e30f;
      float m2 = fmaxf(s0, s1);
#pragma unroll
      for (int off = 1; off < 16; off <<= 1) m2 = fmaxf(m2, __shfl_xor(m2, off));
      float mn = fmaxf(mst[r], m2);
      float a = __builtin_amdgcn_exp2f(mst[r] - mn);
      float p0 = __builtin_amdgcn_exp2f(s0 - mn);
      float p1 = __builtin_amdgcn_exp2f(s1 - mn);
      float ps = p0 + p1;
#pragma unroll
      for (int off = 1; off < 16; off <<= 1) ps += __shfl_xor(ps, off);
      lst[r] = lst[r] * a + ps;
      mst[r] = mn;
      al[r] = a; p0s[r] = p0; p1s[r] = p1;
    }
#pragma unroll
    for (int jt = 0; jt < 4; jt++)
#pragma unroll
      for (int r = 0; r < 4; r++) Oa[jt][r] *= al[r];
    // P: C-layout -> LDS -> A-layout (per m120); same-wave LDS, no barrier needed
#pragma unroll
    for (int r = 0; r < 4; r++) {
      P[wv][(4 * lq + r) * 40 + lm] = (short)f2bf(p0s[r]);
      P[wv][(4 * lq + r) * 40 + 16 + lm] = (short)f2bf(p1s[r]);
    }
    bf16x8 pa = *(const bf16x8*)&P[wv][lm * 40 + 8 * lq];
#pragma unroll
    for (int jt = 0; jt < 4; jt++) {
      bf16x8 vf;  // B-frag: V[k=quad*8+jj][n=16*jt+lm] (transposed gather, L1-served)
#pragma unroll
      for (int jj = 0; jj < 8; jj++) {
        int kk = j0 + 8 * lq + jj; if (kk > T_ - 1) kk = T_ - 1;
        vf[jj] = (short)Vb[base + (size_t)kk * 64 + 16 * jt + lm];
      }
      Oa[jt] = __builtin_amdgcn_mfma_f32_16x16x32_bf16(pa, vf, Oa[jt], 0, 0, 0);
    }
  }
  const int b = bh >> 4, h = bh & 15;
#pragma unroll
  for (int r = 0; r < 4; r++) {
    float inv = 1.0f / lst[r];
    int t = t0 + 4 * lq + r;
#pragma unroll
    for (int jt = 0; jt < 4; jt++) {
      int c = h * 64 + 16 * jt + lm;
      Ob[((size_t)(b * T_ + t)) * 1024 + c] = f2bf(Oa[jt][r] * inv);
    }
  }
}

extern "C" void kernel_launch(void* const* d_in, const int* in_sizes, int n_in,
                              void* d_out, int out_size, void* d_ws, size_t ws_size,
                              hipStream_t stream) {
  const float* x = (const float*)d_in[0];       // [4,2048,1024]
  const float* w_qkv = (const float*)d_in[1];   // [3072,1024]
  const float* w_out = (const float*)d_in[2];   // [1024,1024]
  float* out = (float*)d_out;                   // [4,2048,1024] fp32

  // workspace layout (bf16 = unsigned short), ~72 MB total
  unsigned short* xb = (unsigned short*)d_ws;                // 8192*1024 (reused as attn out)
  unsigned short* wqkvb = xb + (size_t)8192 * 1024;          // 3072*1024
  unsigned short* woutb = wqkvb + (size_t)3072 * 1024;       // 1024*1024
  unsigned short* qb = woutb + (size_t)1024 * 1024;          // 64*2048*64
  unsigned short* kb = qb + (size_t)64 * 2048 * 64;
  unsigned short* vb = kb + (size_t)64 * 2048 * 64;

  cast_f32_bf16<<<8192, 256, 0, stream>>>(x, xb, 8192 * 1024 / 4);
  cast_f32_bf16<<<3072, 256, 0, stream>>>(w_qkv, wqkvb, 3072 * 1024 / 4);
  cast_f32_bf16<<<1024, 256, 0, stream>>>(w_out, woutb, 1024 * 1024 / 4);

  // qkv = x @ w_qkv^T, scattered to q/k/v [B,H,T,D]
  gemm_bt<0><<<dim3(24, 64), 256, 0, stream>>>(xb, wqkvb, qb, kb, vb, nullptr);

  // sliding-window attention -> [B,T,C] bf16 (aliases xb; xb is dead after gemm_qkv)
  attn_swa<<<2048, 256, 0, stream>>>(qb, kb, vb, xb);

  // out = attn @ w_out^T (fp32 store)
  gemm_bt<1><<<dim3(8, 64), 256, 0, stream>>>(xb, woutb, nullptr, nullptr, nullptr, out);
}